// Round 6
// baseline (630.525 us; speedup 1.0000x reference)
//
#include <hip/hip_runtime.h>
#include <math.h>

// DeBERTa disentangled self-attention, fused (MI355X / gfx950).
// B=2, S=2048, D=64, H=12, K_SPAN=512.
// score[i,j] = (q_i.k_j + q_i.pk[c] + k_j.pq[c]) / sqrt(192), c = clip(i-j+512,0,1023)
//
// prep:      fp32 -> bf16 hi/lo split of H|pos, bf16 W, biases (scratch in d_out head).
// proj_gemm: MFMA 16x16x32, X = hi+lo; per-matrix D-orientation so reg-quads are
//            4 consecutive outputs -> packed 8B coalesced stores (V via swapped op order).
// pos_dots:  c2p0/1023[bh][i] = q.pk[0/1023];  p2c0/1023[bh][j] = k.pq[0/1023].
// attn<SPLIT>: split-K flash attention, 1-wave blocks, grid 1536*SPLIT, XCD-swizzled.
//            Fused gather table tbl2[64 j][32 i] u32 {lo=c2p, hi=p2c}, written
//            scatter-side from band MFMAs (bijective jslot mapping) -> 8KB LDS,
//            conflict-free writes AND reads; gather = 32 ds_read_b32.
// combine<SPLIT>: merge partials (m,l,ctx) -> out.

#define S_LEN 2048
#define NH    12
#define TWOK  1024
#define QSZ   3145728   // 24 * 2048 * 64
#define PSZ   786432    // 12 * 1024 * 64
#define POSF  11010048  // 3*QSZ + 2*PSZ (u16 elements)

typedef __bf16 bf16x8 __attribute__((ext_vector_type(8)));
typedef unsigned short u16x8 __attribute__((ext_vector_type(8)));
typedef unsigned short u16x4 __attribute__((ext_vector_type(4)));
typedef float f32x4  __attribute__((ext_vector_type(4)));
typedef float f32x16 __attribute__((ext_vector_type(16)));
typedef unsigned int u32x4 __attribute__((ext_vector_type(4)));

__device__ __forceinline__ unsigned short f2bf(float f) {
  return __builtin_bit_cast(unsigned short, (__bf16)f);
}
__device__ __forceinline__ unsigned pk2bf(float a, float b) {
  return ((unsigned)__builtin_bit_cast(unsigned short, (__bf16)b) << 16)
       | (unsigned)__builtin_bit_cast(unsigned short, (__bf16)a);
}
__device__ __forceinline__ float bf2f(unsigned short h) {
  return __builtin_bit_cast(float, ((unsigned)h) << 16);
}
__device__ __forceinline__ bf16x8 ld_bf8(const unsigned short* p) {
  return __builtin_bit_cast(bf16x8, *(const u16x8*)p);
}

// ---------------------------------------------------------------- prep
__global__ __launch_bounds__(256) void prep_kernel(
    const float* __restrict__ Hx, const float* __restrict__ pos,
    const float* __restrict__ Wq, const float* __restrict__ Wk,
    const float* __restrict__ Wv, const float* __restrict__ Wpk,
    const float* __restrict__ Wpq,
    const float* __restrict__ bq, const float* __restrict__ bk,
    const float* __restrict__ bv, const float* __restrict__ bpk,
    const float* __restrict__ bpq,
    unsigned short* __restrict__ whi, unsigned short* __restrict__ wlo,
    unsigned short* __restrict__ wall, float* __restrict__ ball) {
  int idx = blockIdx.x * 256 + threadIdx.x;
  if (idx < 327680) {                       // H (4096x64) then pos (1024x64): hi/lo split
    float v = (idx < 262144) ? Hx[idx] : pos[idx - 262144];
    __bf16 hi = (__bf16)v;
    float lo = v - (float)hi;
    whi[idx] = __builtin_bit_cast(unsigned short, hi);
    wlo[idx] = f2bf(lo);
  } else if (idx < 573440) {                // W: q,k,v,pk,pq -> bf16, 3840x64
    int k = idx - 327680;
    int mat = k / 49152, off = k - mat * 49152;
    const float* W = mat==0?Wq: mat==1?Wk: mat==2?Wv: mat==3?Wpk:Wpq;
    wall[k] = f2bf(W[off]);
  } else if (idx < 577280) {                // biases, 3840
    int k = idx - 573440;
    int mat = k / 768, off = k - mat * 768;
    const float* B = mat==0?bq: mat==1?bk: mat==2?bv: mat==3?bpk:bpq;
    ball[k] = B[off];
  }
}

// ---------------------------------------------------------------- projection GEMM
// block 256 = 4 waves; tile 64 tokens x 64 oh; wave = 16 oh x 64 tokens.
// q/k/pk/pq: D = mfma(W, X): lane col = token, reg quad = 4 consecutive oh -> 8B stores.
// v:         D = mfma(X, W): lane col = oh(d), reg quad = 4 consecutive tokens -> 8B vT stores.
__global__ __launch_bounds__(256) void proj_gemm(
    const unsigned short* __restrict__ whi, const unsigned short* __restrict__ wlo,
    const unsigned short* __restrict__ wall, const float* __restrict__ ball,
    unsigned short* __restrict__ ws) {
  unsigned short* qg  = ws;
  unsigned short* kg  = ws + QSZ;
  unsigned short* vtg = ws + 2 * QSZ;
  unsigned short* pkg = ws + 3 * QSZ;
  unsigned short* pqg = ws + 3 * QSZ + PSZ;

  int bid = blockIdx.x;
  int rbase, obase, wrow, isA;
  if (bid < 2304) { rbase = (bid / 36) * 64;        obase = (bid % 36) * 64; wrow = obase;        isA = 1; }
  else { int b2 = bid - 2304; rbase = 4096 + (b2 / 24) * 64; obase = (b2 % 24) * 64; wrow = 2304 + obase; isA = 0; }

  int tid = threadIdx.x, w = tid >> 6, l = tid & 63, lg = l >> 4, lr = l & 15;
  int mat = obase / 768;
  int h = (obase % 768) >> 6;              // uniform per block
  int ohrow = wrow + w * 16;               // this wave's 16 W rows

  bf16x8 wf[2];
  #pragma unroll
  for (int ks = 0; ks < 2; ++ks)
    wf[ks] = ld_bf8(wall + (ohrow + lr) * 64 + ks * 32 + 8 * lg);

  if (isA && mat == 2) {
    // ---- V, swapped orientation -> vT packed stores
    float bias = ball[ohrow + lr];
    int d = w * 16 + lr;                   // oh & 63
    #pragma unroll
    for (int tg = 0; tg < 4; ++tg) {
      f32x4 acc = {0.f, 0.f, 0.f, 0.f};
      #pragma unroll
      for (int ks = 0; ks < 2; ++ks) {
        bf16x8 xh = ld_bf8(whi + (rbase + tg * 16 + lr) * 64 + ks * 32 + 8 * lg);
        bf16x8 xl = ld_bf8(wlo + (rbase + tg * 16 + lr) * 64 + ks * 32 + 8 * lg);
        acc = __builtin_amdgcn_mfma_f32_16x16x32_bf16(xh, wf[ks], acc, 0, 0, 0);
        acc = __builtin_amdgcn_mfma_f32_16x16x32_bf16(xl, wf[ks], acc, 0, 0, 0);
      }
      int tok0 = rbase + tg * 16 + 4 * lg;
      int bb = tok0 >> 11, i0 = tok0 & 2047, bh = bb * NH + h;
      u16x4 pv;
      #pragma unroll
      for (int e = 0; e < 4; ++e) pv[e] = f2bf(acc[e] + bias);
      *(u16x4*)(vtg + (size_t)(bh * 64 + d) * S_LEN + i0) = pv;
    }
  } else {
    // ---- q/k/pk/pq, row-major packed stores
    float4 bias4 = *(const float4*)(ball + ohrow + 4 * lg);
    int d0 = w * 16 + 4 * lg;              // oh & 63 quad base
    #pragma unroll
    for (int tg = 0; tg < 4; ++tg) {
      f32x4 acc = {0.f, 0.f, 0.f, 0.f};
      #pragma unroll
      for (int ks = 0; ks < 2; ++ks) {
        bf16x8 xh = ld_bf8(whi + (rbase + tg * 16 + lr) * 64 + ks * 32 + 8 * lg);
        bf16x8 xl = ld_bf8(wlo + (rbase + tg * 16 + lr) * 64 + ks * 32 + 8 * lg);
        acc = __builtin_amdgcn_mfma_f32_16x16x32_bf16(wf[ks], xh, acc, 0, 0, 0);
        acc = __builtin_amdgcn_mfma_f32_16x16x32_bf16(wf[ks], xl, acc, 0, 0, 0);
      }
      int tok = rbase + tg * 16 + lr;
      u16x4 pv;
      pv[0] = f2bf(acc[0] + bias4.x); pv[1] = f2bf(acc[1] + bias4.y);
      pv[2] = f2bf(acc[2] + bias4.z); pv[3] = f2bf(acc[3] + bias4.w);
      if (isA) {
        int bb = tok >> 11, i = tok & 2047, bh = bb * NH + h;
        unsigned short* dst = (mat == 0 ? qg : kg) + (size_t)(bh * S_LEN + i) * 64 + d0;
        *(u16x4*)dst = pv;
      } else {
        int prow = tok - 4096;
        unsigned short* dst = (mat == 0 ? pkg : pqg) + (size_t)(h * TWOK + prow) * 64 + d0;
        *(u16x4*)dst = pv;
      }
    }
  }
}

// ---------------------------------------------------------------- pos_dots
__global__ __launch_bounds__(256) void pos_dots(
    const unsigned short* __restrict__ ws, float* __restrict__ c2p0,
    float* __restrict__ c2p1023, float* __restrict__ p2c0,
    float* __restrict__ p2c1023) {
  int t = blockIdx.x * 256 + threadIdx.x;     // [0, 98304)
  int isK = t >= 49152;
  int row = isK ? t - 49152 : t;              // bh*2048 + i
  int h = (row >> 11) % NH;
  const unsigned short* src = ws + (isK ? QSZ : 0) + row * 64;
  const unsigned short* pA = ws + 3 * QSZ + (isK ? PSZ : 0) + (h * TWOK) * 64;
  const unsigned short* pB = pA + 1023 * 64;
  float a0 = 0.f, a1 = 0.f;
  #pragma unroll
  for (int c = 0; c < 8; ++c) {
    u16x8 xv = *(const u16x8*)(src + c * 8);
    u16x8 av = *(const u16x8*)(pA + c * 8);
    u16x8 bv = *(const u16x8*)(pB + c * 8);
    #pragma unroll
    for (int e = 0; e < 8; ++e) {
      float x = bf2f(xv[e]);
      a0 += x * bf2f(av[e]);
      a1 += x * bf2f(bv[e]);
    }
  }
  if (isK) { p2c0[row] = a0; p2c1023[row] = a1; }
  else     { c2p0[row] = a0; c2p1023[row] = a1; }
}

// ---------------------------------------------------------------- fused attention
// 1 wave/block; grid 1536*SPLIT; bid -> (xcd g, sk, bh, it32). LDS = tbl2 8KB.
// tbl2[j 0..63][i 0..31] u32: lo16 = c2p(i, j0+j), hi16 = p2c(j0+j, i).
template<int SPLIT>
__global__ __launch_bounds__(64, 4) void attn_kernel(
    const unsigned short* __restrict__ ws, float* __restrict__ out,
    unsigned short* __restrict__ ctxP, float* __restrict__ mlP) {
  const unsigned short* qg  = ws;
  const unsigned short* kg  = ws + QSZ;
  const unsigned short* vtg = ws + 2 * QSZ;
  const unsigned short* pkg = ws + 3 * QSZ;
  const unsigned short* pqg = ws + 3 * QSZ + PSZ;
  const float* c2p0g    = (const float*)(ws + POSF);
  const float* c2p1023g = c2p0g + 49152;
  const float* p2c0g    = c2p0g + 98304;
  const float* p2c1023g = c2p0g + 147456;

  __shared__ unsigned int tbl2[64 * 32];       // 8KB

  const int bid = blockIdx.x;
  const int g = bid & 7;                       // ~XCD (round-robin dispatch)
  const int r2 = bid >> 3;
  const int sk = r2 % SPLIT, r = r2 / SPLIT;
  const int bh = 8 * (r % 3) + g;              // XCD g owns bh {g, g+8, g+16}
  const int it32 = r / 3;                      // 0..63
  const int b = bh / NH, h = bh - b * NH;
  const int l = threadIdx.x & 63;
  const int iL = l & 31, h5 = l >> 5;
  const int i0w = it32 * 32;
  const int ig = i0w + iL;

  const unsigned short* qb  = qg  + bh * (S_LEN * 64);
  const unsigned short* kb  = kg  + bh * (S_LEN * 64);
  const unsigned short* vb  = vtg + bh * (64 * S_LEN);
  const unsigned short* pkb = pkg + h * (TWOK * 64);
  const unsigned short* pqb = pqg + h * (TWOK * 64);

  const float CS = 1.4426950408889634f / sqrtf(192.0f);  // log2(e)/sqrt(3*64)

  // Q as B-frag: lane holds Q[col=i=iL][k = kc*16 + 8*h5 + e]
  bf16x8 qf[4];
  #pragma unroll
  for (int kc = 0; kc < 4; ++kc)
    qf[kc] = ld_bf8(qb + ig * 64 + kc * 16 + 8 * h5);

  const float c2pLO = c2p0g[bh * S_LEN + ig];
  const float c2pHI = c2p1023g[bh * S_LEN + ig];

  f32x16 ctx0 = 0.f, ctx1 = 0.f;
  float m_ = -1e30f, l_ = 0.f;

  const int jt0 = sk * (32 / SPLIT);
  const int jt1 = jt0 + (32 / SPLIT);

  for (int jt = jt0; jt < jt1; ++jt) {
    const int j0 = jt * 64;
    const int D0w = 512 + i0w - j0;        // wave-uniform
    const int rlo = D0w - 63;              // raw rel min over tile
    const int rhi = rlo + 94;              // raw rel max

    // K as A-frag (rows j) - reused as B-frag (cols j) for p2c bands
    bf16x8 kf0[4], kf1[4];
    #pragma unroll
    for (int kc = 0; kc < 4; ++kc) {
      kf0[kc] = ld_bf8(kb + (j0 + iL) * 64 + kc * 16 + 8 * h5);
      kf1[kc] = ld_bf8(kb + (j0 + 32 + iL) * 64 + kc * 16 + 8 * h5);
    }
    // V^T frags hoisted
    bf16x8 vf0[4], vf1[4];
    #pragma unroll
    for (int kc = 0; kc < 4; ++kc) {
      vf0[kc] = ld_bf8(vb + (iL) * S_LEN + j0 + kc * 16 + 8 * h5);
      vf1[kc] = ld_bf8(vb + (32 + iL) * S_LEN + j0 + kc * 16 + 8 * h5);
    }

    // QK^T swapped: D[row=j][col=i]; lane: i=iL, j = 32*js + (r&3)+8*(r>>2)+4*h5
    f32x16 s0 = 0.f, s1 = 0.f;
    #pragma unroll
    for (int kc = 0; kc < 4; ++kc) {
      s0 = __builtin_amdgcn_mfma_f32_32x32x16_bf16(kf0[kc], qf[kc], s0, 0, 0, 0);
      s1 = __builtin_amdgcn_mfma_f32_32x32x16_bf16(kf1[kc], qf[kc], s1, 0, 0, 0);
    }

    if (rlo >= 1023) {
      // -------- fully clamped high
      float pa = p2c1023g[bh * S_LEN + j0 + iL];
      float pb = p2c1023g[bh * S_LEN + j0 + 32 + iL];
      #pragma unroll
      for (int rr = 0; rr < 16; ++rr) {
        const int j32 = (rr & 3) + 8 * (rr >> 2) + 4 * h5;
        s0[rr] = (s0[rr] + c2pHI + __shfl(pa, j32)) * CS;
        s1[rr] = (s1[rr] + c2pHI + __shfl(pb, j32)) * CS;
      }
    } else if (rhi <= 0) {
      // -------- fully clamped low
      float pa = p2c0g[bh * S_LEN + j0 + iL];
      float pb = p2c0g[bh * S_LEN + j0 + 32 + iL];
      #pragma unroll
      for (int rr = 0; rr < 16; ++rr) {
        const int j32 = (rr & 3) + 8 * (rr >> 2) + 4 * h5;
        s0[rr] = (s0[rr] + c2pLO + __shfl(pa, j32)) * CS;
        s1[rr] = (s1[rr] + c2pLO + __shfl(pb, j32)) * CS;
      }
    } else {
      // -------- banded path
      const int rminc = rlo < 0 ? 0 : rlo;
      const int rmaxc = rhi > 1023 ? 1023 : rhi;
      const int bstart = rminc > 928 ? 928 : rminc;
      const int nbands = ((rmaxc - bstart) >> 5) + 1;     // <= 3
      const int base = D0w - bstart;
      const int interior = (rlo >= 0) & (rhi <= 1023);

      for (int nb = 0; nb < nbands; ++nb) {
        const int relb0 = nb * 32;
        const bool needC  = (relb0 <= base + 31) && (relb0 + 31 >= base - 63);
        const bool needP0 = (relb0 <= base + 31) && (relb0 + 31 >= base - 31);
        const bool needP1 = (relb0 <= base - 1)  && (relb0 + 31 >= base - 63);
        const int rrow = bstart + relb0 + iL;

        if (needC) {
          f32x16 ac = 0.f;
          #pragma unroll
          for (int kc = 0; kc < 4; ++kc) {
            bf16x8 fk = ld_bf8(pkb + rrow * 64 + kc * 16 + 8 * h5);
            ac = __builtin_amdgcn_mfma_f32_32x32x16_bf16(fk, qf[kc], ac, 0, 0, 0);
          }
          // scatter: value (i=iL, rel) -> slot [js = base+iL-relb][iL], low u16
          #pragma unroll
          for (int q4 = 0; q4 < 4; ++q4) {
            #pragma unroll
            for (int e = 0; e < 4; ++e) {
              const int relb = relb0 + 8 * q4 + 4 * h5 + e;
              const int js = base + iL - relb;
              if (js >= 0 && js < 64)
                ((unsigned short*)tbl2)[(js * 32 + iL) * 2] = f2bf(ac[4 * q4 + e]);
            }
          }
        }
        if (needP0 | needP1) {
          f32x16 a0 = 0.f, a1 = 0.f;
          #pragma unroll
          for (int kc = 0; kc < 4; ++kc) {
            bf16x8 fq = ld_bf8(pqb + rrow * 64 + kc * 16 + 8 * h5);
            if (needP0) a0 = __builtin_amdgcn_mfma_f32_32x32x16_bf16(fq, kf0[kc], a0, 0, 0, 0);
            if (needP1) a1 = __builtin_amdgcn_mfma_f32_32x32x16_bf16(fq, kf1[kc], a1, 0, 0, 0);
          }
          // scatter: value (j=jc, rel) -> slot [jc][i2 = relb+jc-base], high u16
          #pragma unroll
          for (int q4 = 0; q4 < 4; ++q4) {
            #pragma unroll
            for (int e = 0; e < 4; ++e) {
              const int relb = relb0 + 8 * q4 + 4 * h5 + e;
              if (needP0) {
                const int i2 = relb + iL - base;
                if (i2 >= 0 && i2 < 32)
                  ((unsigned short*)tbl2)[(iL * 32 + i2) * 2 + 1] = f2bf(a0[4 * q4 + e]);
              }
              if (needP1) {
                const int i2 = relb + 32 + iL - base;
                if (i2 >= 0 && i2 < 32)
                  ((unsigned short*)tbl2)[((32 + iL) * 32 + i2) * 2 + 1] = f2bf(a1[4 * q4 + e]);
              }
            }
          }
        }
      }
      asm volatile("s_waitcnt lgkmcnt(0)" ::: "memory");  // wave-local write->read

      if (interior) {
        #pragma unroll
        for (int rr = 0; rr < 16; ++rr) {
          const int j32 = (rr & 3) + 8 * (rr >> 2) + 4 * h5;
          const unsigned t0 = tbl2[j32 * 32 + iL];
          const unsigned t1 = tbl2[(32 + j32) * 32 + iL];
          s0[rr] = (s0[rr] + bf2f((unsigned short)t0) + bf2f((unsigned short)(t0 >> 16))) * CS;
          s1[rr] = (s1[rr] + bf2f((unsigned short)t1) + bf2f((unsigned short)(t1 >> 16))) * CS;
        }
      } else {
        const int D0 = D0w + iL;
        float paL = p2c0g[bh * S_LEN + j0 + iL];
        float paH = p2c1023g[bh * S_LEN + j0 + iL];
        float pbL = p2c0g[bh * S_LEN + j0 + 32 + iL];
        float pbH = p2c1023g[bh * S_LEN + j0 + 32 + iL];
        #pragma unroll
        for (int rr = 0; rr < 16; ++rr) {
          const int j32 = (rr & 3) + 8 * (rr >> 2) + 4 * h5;
          const int raw0 = D0 - j32, raw1 = D0 - 32 - j32;
          const unsigned t0 = tbl2[j32 * 32 + iL];
          const unsigned t1 = tbl2[(32 + j32) * 32 + iL];
          const float saL = __shfl(paL, j32), saH = __shfl(paH, j32);
          const float sbL = __shfl(pbL, j32), sbH = __shfl(pbH, j32);
          float c0 = raw0 <= 0 ? c2pLO : (raw0 >= 1023 ? c2pHI : bf2f((unsigned short)t0));
          float p0 = raw0 <= 0 ? saL   : (raw0 >= 1023 ? saH   : bf2f((unsigned short)(t0 >> 16)));
          float c1 = raw1 <= 0 ? c2pLO : (raw1 >= 1023 ? c2pHI : bf2f((unsigned short)t1));
          float p1 = raw1 <= 0 ? sbL   : (raw1 >= 1023 ? sbH   : bf2f((unsigned short)(t1 >> 16)));
          s0[rr] = (s0[rr] + c0 + p0) * CS;
          s1[rr] = (s1[rr] + c1 + p1) * CS;
        }
      }
    }

    // -------- online softmax (lane owns full row i)
    float vmax = s0[0];
    #pragma unroll
    for (int rr = 1; rr < 16; ++rr) vmax = fmaxf(vmax, s0[rr]);
    #pragma unroll
    for (int rr = 0; rr < 16; ++rr) vmax = fmaxf(vmax, s1[rr]);
    vmax = fmaxf(vmax, __shfl_xor(vmax, 32));
    float mx = fmaxf(m_, vmax);
    float fs = __builtin_amdgcn_exp2f(m_ - mx);
    m_ = mx;
    float sum = 0.f;
    #pragma unroll
    for (int rr = 0; rr < 16; ++rr) { s0[rr] = __builtin_amdgcn_exp2f(s0[rr] - mx); sum += s0[rr]; }
    #pragma unroll
    for (int rr = 0; rr < 16; ++rr) { s1[rr] = __builtin_amdgcn_exp2f(s1[rr] - mx); sum += s1[rr]; }
    sum += __shfl_xor(sum, 32);
    l_ = l_ * fs + sum;
    if (!__all(fs == 1.0f)) { ctx0 *= fs; ctx1 *= fs; }   // defer-rescale (exact)

    // -------- repack P -> B-frags: cvt-pack + cross-half shfl + select
    bf16x8 pf[4];
    #pragma unroll
    for (int kc = 0; kc < 4; ++kc) {
      const int c = kc & 1;
      const f32x16& sj = (kc >> 1) ? s1 : s0;
      unsigned X0 = pk2bf(sj[8*c+0], sj[8*c+1]);
      unsigned X1 = pk2bf(sj[8*c+2], sj[8*c+3]);
      unsigned Y0 = pk2bf(sj[8*c+4], sj[8*c+5]);
      unsigned Y1 = pk2bf(sj[8*c+6], sj[8*c+7]);
      unsigned sx0 = (unsigned)__shfl_xor((int)X0, 32);
      unsigned sx1 = (unsigned)__shfl_xor((int)X1, 32);
      unsigned sy0 = (unsigned)__shfl_xor((int)Y0, 32);
      unsigned sy1 = (unsigned)__shfl_xor((int)Y1, 32);
      u32x4 f;
      f[0] = h5 ? sy0 : X0;
      f[1] = h5 ? sy1 : X1;
      f[2] = h5 ? Y0 : sx0;
      f[3] = h5 ? Y1 : sx1;
      pf[kc] = __builtin_bit_cast(bf16x8, f);
    }

    // -------- PV: ctx = mfma(V^T, P) -> D[row=d][col=i]; lane owns ctx row i
    #pragma unroll
    for (int kc = 0; kc < 4; ++kc) {
      ctx0 = __builtin_amdgcn_mfma_f32_32x32x16_bf16(vf0[kc], pf[kc], ctx0, 0, 0, 0);
      ctx1 = __builtin_amdgcn_mfma_f32_32x32x16_bf16(vf1[kc], pf[kc], ctx1, 0, 0, 0);
    }
  }

  if constexpr (SPLIT == 1) {
    // -------- epilogue: lane owns row i = ig -> float4 stores
    float inv = 1.0f / l_;
    float* ob = out + (b * S_LEN + ig) * 768 + h * 64;
    #pragma unroll
    for (int q4 = 0; q4 < 4; ++q4) {
      float4 o0 = {ctx0[4*q4+0]*inv, ctx0[4*q4+1]*inv, ctx0[4*q4+2]*inv, ctx0[4*q4+3]*inv};
      *(float4*)(ob + 8 * q4 + 4 * h5) = o0;
      float4 o1 = {ctx1[4*q4+0]*inv, ctx1[4*q4+1]*inv, ctx1[4*q4+2]*inv, ctx1[4*q4+3]*inv};
      *(float4*)(ob + 32 + 8 * q4 + 4 * h5) = o1;
    }
  } else {
    // -------- partials: bf16 ctx + f32 (m,l)
    const int rowg = ((bh * 64 + it32) * SPLIT + sk) * 32 + iL;
    unsigned short* cp = ctxP + (size_t)rowg * 64;
    #pragma unroll
    for (int q4 = 0; q4 < 4; ++q4) {
      u16x4 p0, p1;
      #pragma unroll
      for (int e = 0; e < 4; ++e) { p0[e] = f2bf(ctx0[4*q4+e]); p1[e] = f2bf(ctx1[4*q4+e]); }
      *(u16x4*)(cp + 8 * q4 + 4 * h5) = p0;
      *(u16x4*)(cp + 32 + 8 * q4 + 4 * h5) = p1;
    }
    ((float2*)mlP)[rowg] = make_float2(m_, l_);
  }
}

// ---------------------------------------------------------------- combine
template<int SPLIT>
__global__ __launch_bounds__(256) void combine_kernel(
    const unsigned short* __restrict__ ctxP, const float* __restrict__ mlP,
    float* __restrict__ out) {
  int t = blockIdx.x * 256 + threadIdx.x;      // < 786432
  int row = t >> 4, dc = t & 15;
  int bh = row >> 11, i = row & 2047;
  int it32 = i >> 5, iL = i & 31;
  int pbase = ((bh * 64 + it32) * SPLIT) * 32 + iL;
  float m[SPLIT], lv[SPLIT];
  float M = -1e30f;
  #pragma unroll
  for (int s = 0; s < SPLIT; ++s) {
    float2 ml = ((const float2*)mlP)[pbase + s * 32];
    m[s] = ml.x; lv[s] = ml.y;
    M = fmaxf(M, ml.x);
  }
  float L = 0.f, w[SPLIT];
  #pragma unroll
  for (int s = 0; s < SPLIT; ++s) { w[s] = exp2f(m[s] - M); L += lv[s] * w[s]; }
  float4 o = {0.f, 0.f, 0.f, 0.f};
  #pragma unroll
  for (int s = 0; s < SPLIT; ++s) {
    u16x4 c = *(const u16x4*)(ctxP + (size_t)(pbase + s * 32) * 64 + dc * 4);
    o.x += bf2f(c[0]) * w[s]; o.y += bf2f(c[1]) * w[s];
    o.z += bf2f(c[2]) * w[s]; o.w += bf2f(c[3]) * w[s];
  }
  float invL = 1.0f / L;
  int b = bh / NH, h = bh - b * NH;
  float* op = out + (size_t)(b * S_LEN + i) * 768 + h * 64 + dc * 4;
  *(float4*)op = make_float4(o.x * invL, o.y * invL, o.z * invL, o.w * invL);
}

extern "C" void kernel_launch(void* const* d_in, const int* in_sizes, int n_in,
                              void* d_out, int out_size, void* d_ws, size_t ws_size,
                              hipStream_t stream) {
  (void)in_sizes; (void)n_in; (void)out_size;
  const float* Hx  = (const float*)d_in[0];
  const float* pos = (const float*)d_in[1];
  // d_in[2] = relative_pos: deterministic (i-j), recomputed inline -> unused
  const float* Wq  = (const float*)d_in[3];  const float* bq  = (const float*)d_in[4];
  const float* Wk  = (const float*)d_in[5];  const float* bk  = (const float*)d_in[6];
  const float* Wv  = (const float*)d_in[7];  const float* bv  = (const float*)d_in[8];
  const float* Wpq = (const float*)d_in[9];  const float* bpq = (const float*)d_in[10];
  const float* Wpk = (const float*)d_in[11]; const float* bpk = (const float*)d_in[12];
  unsigned short* ws = (unsigned short*)d_ws;

  // prep scratch lives in d_out's head (attn/combine rewrite all of d_out later)
  unsigned short* scratch = (unsigned short*)d_out;
  unsigned short* whi  = scratch;            // 327680 u16
  unsigned short* wlo  = scratch + 327680;   // 327680 u16
  unsigned short* wall = scratch + 655360;   // 245760 u16
  float*          ball = (float*)(scratch + 901120);  // 3840 f32

  float* c2p0g    = (float*)(ws + POSF);
  float* c2p1023g = c2p0g + 49152;
  float* p2c0g    = c2p0g + 98304;
  float* p2c1023g = c2p0g + 147456;

  // split-K partials after pos vecs
  const size_t base_u16 = POSF + 393216;     // 11,403,264 u16 = 22,806,528 B
  const size_t unit_bytes = 6684672;         // per split: ctx 6,291,456 + ml 393,216
  int SPLIT = (ws_size >= base_u16 * 2 + 4 * unit_bytes) ? 4
            : (ws_size >= base_u16 * 2 + 2 * unit_bytes) ? 2 : 1;
  unsigned short* ctxP = ws + base_u16;
  float* mlP = (float*)(ctxP + (size_t)SPLIT * 3145728);

  prep_kernel<<<2255, 256, 0, stream>>>(Hx, pos, Wq, Wk, Wv, Wpk, Wpq,
                                        bq, bk, bv, bpk, bpq, whi, wlo, wall, ball);
  proj_gemm<<<2688, 256, 0, stream>>>(whi, wlo, wall, ball, ws);
  pos_dots<<<384, 256, 0, stream>>>(ws, c2p0g, c2p1023g, p2c0g, p2c1023g);

  float* outf = (float*)d_out;
  if (SPLIT == 4) {
    attn_kernel<4><<<1536 * 4, 64, 0, stream>>>(ws, outf, ctxP, mlP);
    combine_kernel<4><<<3072, 256, 0, stream>>>(ctxP, mlP, outf);
  } else if (SPLIT == 2) {
    attn_kernel<2><<<1536 * 2, 64, 0, stream>>>(ws, outf, ctxP, mlP);
    combine_kernel<2><<<3072, 256, 0, stream>>>(ctxP, mlP, outf);
  } else {
    attn_kernel<1><<<1536, 64, 0, stream>>>(ws, outf, ctxP, mlP);
  }
}

// Round 7
// 430.797 us; speedup vs baseline: 1.4636x; 1.4636x over previous
//
#include <hip/hip_runtime.h>
#include <math.h>

// DeBERTa disentangled self-attention, fused (MI355X / gfx950).
// B=2, S=2048, D=64, H=12, K_SPAN=512.
// score[i,j] = (q_i.k_j + q_i.pk[c] + k_j.pq[c]) / sqrt(192), c = clip(i-j+512,0,1023)
//
// prep:      fp32 -> bf16 hi/lo split of H|pos, bf16 W, biases (scratch in d_out head).
// proj_gemm: MFMA 16x16x32, X = hi+lo; per-matrix D-orientation so reg-quads are
//            4 consecutive outputs -> packed 8B coalesced stores (V via swapped op order).
// pos_dots:  c2p0/1023[bh][i] = q.pk[0/1023];  p2c0/1023[bh][j] = k.pq[0/1023].
// attn<SPLIT>: split-K flash attention, 1-wave blocks, grid 1536*SPLIT, XCD-swizzled.
//            Fused gather table tbl2[64 j][32 i] u32 {lo=c2p, hi=p2c}, scatter-written
//            from band MFMAs -> 8KB LDS, conflict-free (round-6 PMC: 0 conflicts).
//            NOTE launch bounds (64,2): (64,4) capped VGPR at 64 -> 1.85GB spill
//            traffic, 2.2x regression (round 6). (64,2) -> 128 VGPR, no spill.
// combine<SPLIT>: merge partials (m,l,ctx) -> out.

#define S_LEN 2048
#define NH    12
#define TWOK  1024
#define QSZ   3145728   // 24 * 2048 * 64
#define PSZ   786432    // 12 * 1024 * 64
#define POSF  11010048  // 3*QSZ + 2*PSZ (u16 elements)

typedef __bf16 bf16x8 __attribute__((ext_vector_type(8)));
typedef unsigned short u16x8 __attribute__((ext_vector_type(8)));
typedef unsigned short u16x4 __attribute__((ext_vector_type(4)));
typedef float f32x4  __attribute__((ext_vector_type(4)));
typedef float f32x16 __attribute__((ext_vector_type(16)));
typedef unsigned int u32x4 __attribute__((ext_vector_type(4)));

__device__ __forceinline__ unsigned short f2bf(float f) {
  return __builtin_bit_cast(unsigned short, (__bf16)f);
}
__device__ __forceinline__ unsigned pk2bf(float a, float b) {
  return ((unsigned)__builtin_bit_cast(unsigned short, (__bf16)b) << 16)
       | (unsigned)__builtin_bit_cast(unsigned short, (__bf16)a);
}
__device__ __forceinline__ float bf2f(unsigned short h) {
  return __builtin_bit_cast(float, ((unsigned)h) << 16);
}
__device__ __forceinline__ bf16x8 ld_bf8(const unsigned short* p) {
  return __builtin_bit_cast(bf16x8, *(const u16x8*)p);
}

// ---------------------------------------------------------------- prep
__global__ __launch_bounds__(256) void prep_kernel(
    const float* __restrict__ Hx, const float* __restrict__ pos,
    const float* __restrict__ Wq, const float* __restrict__ Wk,
    const float* __restrict__ Wv, const float* __restrict__ Wpk,
    const float* __restrict__ Wpq,
    const float* __restrict__ bq, const float* __restrict__ bk,
    const float* __restrict__ bv, const float* __restrict__ bpk,
    const float* __restrict__ bpq,
    unsigned short* __restrict__ whi, unsigned short* __restrict__ wlo,
    unsigned short* __restrict__ wall, float* __restrict__ ball) {
  int idx = blockIdx.x * 256 + threadIdx.x;
  if (idx < 327680) {                       // H (4096x64) then pos (1024x64): hi/lo split
    float v = (idx < 262144) ? Hx[idx] : pos[idx - 262144];
    __bf16 hi = (__bf16)v;
    float lo = v - (float)hi;
    whi[idx] = __builtin_bit_cast(unsigned short, hi);
    wlo[idx] = f2bf(lo);
  } else if (idx < 573440) {                // W: q,k,v,pk,pq -> bf16, 3840x64
    int k = idx - 327680;
    int mat = k / 49152, off = k - mat * 49152;
    const float* W = mat==0?Wq: mat==1?Wk: mat==2?Wv: mat==3?Wpk:Wpq;
    wall[k] = f2bf(W[off]);
  } else if (idx < 577280) {                // biases, 3840
    int k = idx - 573440;
    int mat = k / 768, off = k - mat * 768;
    const float* B = mat==0?bq: mat==1?bk: mat==2?bv: mat==3?bpk:bpq;
    ball[k] = B[off];
  }
}

// ---------------------------------------------------------------- projection GEMM
// block 256 = 4 waves; tile 64 tokens x 64 oh; wave = 16 oh x 64 tokens.
// q/k/pk/pq: D = mfma(W, X): lane col = token, reg quad = 4 consecutive oh -> 8B stores.
// v:         D = mfma(X, W): lane col = oh(d), reg quad = 4 consecutive tokens -> 8B vT stores.
__global__ __launch_bounds__(256) void proj_gemm(
    const unsigned short* __restrict__ whi, const unsigned short* __restrict__ wlo,
    const unsigned short* __restrict__ wall, const float* __restrict__ ball,
    unsigned short* __restrict__ ws) {
  unsigned short* qg  = ws;
  unsigned short* kg  = ws + QSZ;
  unsigned short* vtg = ws + 2 * QSZ;
  unsigned short* pkg = ws + 3 * QSZ;
  unsigned short* pqg = ws + 3 * QSZ + PSZ;

  int bid = blockIdx.x;
  int rbase, obase, wrow, isA;
  if (bid < 2304) { rbase = (bid / 36) * 64;        obase = (bid % 36) * 64; wrow = obase;        isA = 1; }
  else { int b2 = bid - 2304; rbase = 4096 + (b2 / 24) * 64; obase = (b2 % 24) * 64; wrow = 2304 + obase; isA = 0; }

  int tid = threadIdx.x, w = tid >> 6, l = tid & 63, lg = l >> 4, lr = l & 15;
  int mat = obase / 768;
  int h = (obase % 768) >> 6;              // uniform per block
  int ohrow = wrow + w * 16;               // this wave's 16 W rows

  bf16x8 wf[2];
  #pragma unroll
  for (int ks = 0; ks < 2; ++ks)
    wf[ks] = ld_bf8(wall + (ohrow + lr) * 64 + ks * 32 + 8 * lg);

  if (isA && mat == 2) {
    // ---- V, swapped orientation -> vT packed stores
    float bias = ball[ohrow + lr];
    int d = w * 16 + lr;                   // oh & 63
    #pragma unroll
    for (int tg = 0; tg < 4; ++tg) {
      f32x4 acc = {0.f, 0.f, 0.f, 0.f};
      #pragma unroll
      for (int ks = 0; ks < 2; ++ks) {
        bf16x8 xh = ld_bf8(whi + (rbase + tg * 16 + lr) * 64 + ks * 32 + 8 * lg);
        bf16x8 xl = ld_bf8(wlo + (rbase + tg * 16 + lr) * 64 + ks * 32 + 8 * lg);
        acc = __builtin_amdgcn_mfma_f32_16x16x32_bf16(xh, wf[ks], acc, 0, 0, 0);
        acc = __builtin_amdgcn_mfma_f32_16x16x32_bf16(xl, wf[ks], acc, 0, 0, 0);
      }
      int tok0 = rbase + tg * 16 + 4 * lg;
      int bb = tok0 >> 11, i0 = tok0 & 2047, bh = bb * NH + h;
      u16x4 pv;
      #pragma unroll
      for (int e = 0; e < 4; ++e) pv[e] = f2bf(acc[e] + bias);
      *(u16x4*)(vtg + (size_t)(bh * 64 + d) * S_LEN + i0) = pv;
    }
  } else {
    // ---- q/k/pk/pq, row-major packed stores
    float4 bias4 = *(const float4*)(ball + ohrow + 4 * lg);
    int d0 = w * 16 + 4 * lg;              // oh & 63 quad base
    #pragma unroll
    for (int tg = 0; tg < 4; ++tg) {
      f32x4 acc = {0.f, 0.f, 0.f, 0.f};
      #pragma unroll
      for (int ks = 0; ks < 2; ++ks) {
        bf16x8 xh = ld_bf8(whi + (rbase + tg * 16 + lr) * 64 + ks * 32 + 8 * lg);
        bf16x8 xl = ld_bf8(wlo + (rbase + tg * 16 + lr) * 64 + ks * 32 + 8 * lg);
        acc = __builtin_amdgcn_mfma_f32_16x16x32_bf16(wf[ks], xh, acc, 0, 0, 0);
        acc = __builtin_amdgcn_mfma_f32_16x16x32_bf16(wf[ks], xl, acc, 0, 0, 0);
      }
      int tok = rbase + tg * 16 + lr;
      u16x4 pv;
      pv[0] = f2bf(acc[0] + bias4.x); pv[1] = f2bf(acc[1] + bias4.y);
      pv[2] = f2bf(acc[2] + bias4.z); pv[3] = f2bf(acc[3] + bias4.w);
      if (isA) {
        int bb = tok >> 11, i = tok & 2047, bh = bb * NH + h;
        unsigned short* dst = (mat == 0 ? qg : kg) + (size_t)(bh * S_LEN + i) * 64 + d0;
        *(u16x4*)dst = pv;
      } else {
        int prow = tok - 4096;
        unsigned short* dst = (mat == 0 ? pkg : pqg) + (size_t)(h * TWOK + prow) * 64 + d0;
        *(u16x4*)dst = pv;
      }
    }
  }
}

// ---------------------------------------------------------------- pos_dots
__global__ __launch_bounds__(256) void pos_dots(
    const unsigned short* __restrict__ ws, float* __restrict__ c2p0,
    float* __restrict__ c2p1023, float* __restrict__ p2c0,
    float* __restrict__ p2c1023) {
  int t = blockIdx.x * 256 + threadIdx.x;     // [0, 98304)
  int isK = t >= 49152;
  int row = isK ? t - 49152 : t;              // bh*2048 + i
  int h = (row >> 11) % NH;
  const unsigned short* src = ws + (isK ? QSZ : 0) + row * 64;
  const unsigned short* pA = ws + 3 * QSZ + (isK ? PSZ : 0) + (h * TWOK) * 64;
  const unsigned short* pB = pA + 1023 * 64;
  float a0 = 0.f, a1 = 0.f;
  #pragma unroll
  for (int c = 0; c < 8; ++c) {
    u16x8 xv = *(const u16x8*)(src + c * 8);
    u16x8 av = *(const u16x8*)(pA + c * 8);
    u16x8 bv = *(const u16x8*)(pB + c * 8);
    #pragma unroll
    for (int e = 0; e < 8; ++e) {
      float x = bf2f(xv[e]);
      a0 += x * bf2f(av[e]);
      a1 += x * bf2f(bv[e]);
    }
  }
  if (isK) { p2c0[row] = a0; p2c1023[row] = a1; }
  else     { c2p0[row] = a0; c2p1023[row] = a1; }
}

// ---------------------------------------------------------------- fused attention
// 1 wave/block; grid 1536*SPLIT; bid -> (xcd g, sk, bh, it32). LDS = tbl2 8KB.
// tbl2[j 0..63][i 0..31] u32: lo16 = c2p(i, j0+j), hi16 = p2c(j0+j, i).
template<int SPLIT>
__global__ __launch_bounds__(64, 2) void attn_kernel(
    const unsigned short* __restrict__ ws, float* __restrict__ out,
    unsigned short* __restrict__ ctxP, float* __restrict__ mlP) {
  const unsigned short* qg  = ws;
  const unsigned short* kg  = ws + QSZ;
  const unsigned short* vtg = ws + 2 * QSZ;
  const unsigned short* pkg = ws + 3 * QSZ;
  const unsigned short* pqg = ws + 3 * QSZ + PSZ;
  const float* c2p0g    = (const float*)(ws + POSF);
  const float* c2p1023g = c2p0g + 49152;
  const float* p2c0g    = c2p0g + 98304;
  const float* p2c1023g = c2p0g + 147456;

  __shared__ unsigned int tbl2[64 * 32];       // 8KB

  const int bid = blockIdx.x;
  const int g = bid & 7;                       // ~XCD (round-robin dispatch)
  const int r2 = bid >> 3;
  const int sk = r2 % SPLIT, r = r2 / SPLIT;
  const int bh = 8 * (r % 3) + g;              // XCD g owns bh {g, g+8, g+16}
  const int it32 = r / 3;                      // 0..63
  const int b = bh / NH, h = bh - b * NH;
  const int l = threadIdx.x & 63;
  const int iL = l & 31, h5 = l >> 5;
  const int i0w = it32 * 32;
  const int ig = i0w + iL;

  const unsigned short* qb  = qg  + bh * (S_LEN * 64);
  const unsigned short* kb  = kg  + bh * (S_LEN * 64);
  const unsigned short* vb  = vtg + bh * (64 * S_LEN);
  const unsigned short* pkb = pkg + h * (TWOK * 64);
  const unsigned short* pqb = pqg + h * (TWOK * 64);

  const float CS = 1.4426950408889634f / sqrtf(192.0f);  // log2(e)/sqrt(3*64)

  // Q as B-frag: lane holds Q[col=i=iL][k = kc*16 + 8*h5 + e]
  bf16x8 qf[4];
  #pragma unroll
  for (int kc = 0; kc < 4; ++kc)
    qf[kc] = ld_bf8(qb + ig * 64 + kc * 16 + 8 * h5);

  const float c2pLO = c2p0g[bh * S_LEN + ig];
  const float c2pHI = c2p1023g[bh * S_LEN + ig];

  f32x16 ctx0 = 0.f, ctx1 = 0.f;
  float m_ = -1e30f, l_ = 0.f;

  const int jt0 = sk * (32 / SPLIT);
  const int jt1 = jt0 + (32 / SPLIT);

  for (int jt = jt0; jt < jt1; ++jt) {
    const int j0 = jt * 64;
    const int D0w = 512 + i0w - j0;        // wave-uniform
    const int rlo = D0w - 63;              // raw rel min over tile
    const int rhi = rlo + 94;              // raw rel max

    // K as A-frag (rows j) - reused as B-frag (cols j) for p2c bands
    bf16x8 kf0[4], kf1[4];
    #pragma unroll
    for (int kc = 0; kc < 4; ++kc) {
      kf0[kc] = ld_bf8(kb + (j0 + iL) * 64 + kc * 16 + 8 * h5);
      kf1[kc] = ld_bf8(kb + (j0 + 32 + iL) * 64 + kc * 16 + 8 * h5);
    }
    // V^T frags hoisted
    bf16x8 vf0[4], vf1[4];
    #pragma unroll
    for (int kc = 0; kc < 4; ++kc) {
      vf0[kc] = ld_bf8(vb + (iL) * S_LEN + j0 + kc * 16 + 8 * h5);
      vf1[kc] = ld_bf8(vb + (32 + iL) * S_LEN + j0 + kc * 16 + 8 * h5);
    }

    // QK^T swapped: D[row=j][col=i]; lane: i=iL, j = 32*js + (r&3)+8*(r>>2)+4*h5
    f32x16 s0 = 0.f, s1 = 0.f;
    #pragma unroll
    for (int kc = 0; kc < 4; ++kc) {
      s0 = __builtin_amdgcn_mfma_f32_32x32x16_bf16(kf0[kc], qf[kc], s0, 0, 0, 0);
      s1 = __builtin_amdgcn_mfma_f32_32x32x16_bf16(kf1[kc], qf[kc], s1, 0, 0, 0);
    }

    if (rlo >= 1023) {
      // -------- fully clamped high
      float pa = p2c1023g[bh * S_LEN + j0 + iL];
      float pb = p2c1023g[bh * S_LEN + j0 + 32 + iL];
      #pragma unroll
      for (int rr = 0; rr < 16; ++rr) {
        const int j32 = (rr & 3) + 8 * (rr >> 2) + 4 * h5;
        s0[rr] = (s0[rr] + c2pHI + __shfl(pa, j32)) * CS;
        s1[rr] = (s1[rr] + c2pHI + __shfl(pb, j32)) * CS;
      }
    } else if (rhi <= 0) {
      // -------- fully clamped low
      float pa = p2c0g[bh * S_LEN + j0 + iL];
      float pb = p2c0g[bh * S_LEN + j0 + 32 + iL];
      #pragma unroll
      for (int rr = 0; rr < 16; ++rr) {
        const int j32 = (rr & 3) + 8 * (rr >> 2) + 4 * h5;
        s0[rr] = (s0[rr] + c2pLO + __shfl(pa, j32)) * CS;
        s1[rr] = (s1[rr] + c2pLO + __shfl(pb, j32)) * CS;
      }
    } else {
      // -------- banded path
      const int rminc = rlo < 0 ? 0 : rlo;
      const int rmaxc = rhi > 1023 ? 1023 : rhi;
      const int bstart = rminc > 928 ? 928 : rminc;
      const int nbands = ((rmaxc - bstart) >> 5) + 1;     // <= 3
      const int base = D0w - bstart;
      const int interior = (rlo >= 0) & (rhi <= 1023);

      for (int nb = 0; nb < nbands; ++nb) {
        const int relb0 = nb * 32;
        const bool needC  = (relb0 <= base + 31) && (relb0 + 31 >= base - 63);
        const bool needP0 = (relb0 <= base + 31) && (relb0 + 31 >= base - 31);
        const bool needP1 = (relb0 <= base - 1)  && (relb0 + 31 >= base - 63);
        const int rrow = bstart + relb0 + iL;

        if (needC) {
          f32x16 ac = 0.f;
          #pragma unroll
          for (int kc = 0; kc < 4; ++kc) {
            bf16x8 fk = ld_bf8(pkb + rrow * 64 + kc * 16 + 8 * h5);
            ac = __builtin_amdgcn_mfma_f32_32x32x16_bf16(fk, qf[kc], ac, 0, 0, 0);
          }
          // scatter: value (i=iL, rel) -> slot [js = base+iL-relb][iL], low u16
          #pragma unroll
          for (int q4 = 0; q4 < 4; ++q4) {
            #pragma unroll
            for (int e = 0; e < 4; ++e) {
              const int relb = relb0 + 8 * q4 + 4 * h5 + e;
              const int js = base + iL - relb;
              if (js >= 0 && js < 64)
                ((unsigned short*)tbl2)[(js * 32 + iL) * 2] = f2bf(ac[4 * q4 + e]);
            }
          }
        }
        if (needP0 | needP1) {
          f32x16 a0 = 0.f, a1 = 0.f;
          #pragma unroll
          for (int kc = 0; kc < 4; ++kc) {
            bf16x8 fq = ld_bf8(pqb + rrow * 64 + kc * 16 + 8 * h5);
            if (needP0) a0 = __builtin_amdgcn_mfma_f32_32x32x16_bf16(fq, kf0[kc], a0, 0, 0, 0);
            if (needP1) a1 = __builtin_amdgcn_mfma_f32_32x32x16_bf16(fq, kf1[kc], a1, 0, 0, 0);
          }
          // scatter: value (j=jc, rel) -> slot [jc][i2 = relb+jc-base], high u16
          #pragma unroll
          for (int q4 = 0; q4 < 4; ++q4) {
            #pragma unroll
            for (int e = 0; e < 4; ++e) {
              const int relb = relb0 + 8 * q4 + 4 * h5 + e;
              if (needP0) {
                const int i2 = relb + iL - base;
                if (i2 >= 0 && i2 < 32)
                  ((unsigned short*)tbl2)[(iL * 32 + i2) * 2 + 1] = f2bf(a0[4 * q4 + e]);
              }
              if (needP1) {
                const int i2 = relb + 32 + iL - base;
                if (i2 >= 0 && i2 < 32)
                  ((unsigned short*)tbl2)[((32 + iL) * 32 + i2) * 2 + 1] = f2bf(a1[4 * q4 + e]);
              }
            }
          }
        }
      }
      asm volatile("s_waitcnt lgkmcnt(0)" ::: "memory");  // wave-local write->read

      if (interior) {
        #pragma unroll
        for (int rr = 0; rr < 16; ++rr) {
          const int j32 = (rr & 3) + 8 * (rr >> 2) + 4 * h5;
          const unsigned t0 = tbl2[j32 * 32 + iL];
          const unsigned t1 = tbl2[(32 + j32) * 32 + iL];
          s0[rr] = (s0[rr] + bf2f((unsigned short)t0) + bf2f((unsigned short)(t0 >> 16))) * CS;
          s1[rr] = (s1[rr] + bf2f((unsigned short)t1) + bf2f((unsigned short)(t1 >> 16))) * CS;
        }
      } else {
        const int D0 = D0w + iL;
        float paL = p2c0g[bh * S_LEN + j0 + iL];
        float paH = p2c1023g[bh * S_LEN + j0 + iL];
        float pbL = p2c0g[bh * S_LEN + j0 + 32 + iL];
        float pbH = p2c1023g[bh * S_LEN + j0 + 32 + iL];
        #pragma unroll
        for (int rr = 0; rr < 16; ++rr) {
          const int j32 = (rr & 3) + 8 * (rr >> 2) + 4 * h5;
          const int raw0 = D0 - j32, raw1 = D0 - 32 - j32;
          const unsigned t0 = tbl2[j32 * 32 + iL];
          const unsigned t1 = tbl2[(32 + j32) * 32 + iL];
          const float saL = __shfl(paL, j32), saH = __shfl(paH, j32);
          const float sbL = __shfl(pbL, j32), sbH = __shfl(pbH, j32);
          float c0 = raw0 <= 0 ? c2pLO : (raw0 >= 1023 ? c2pHI : bf2f((unsigned short)t0));
          float p0 = raw0 <= 0 ? saL   : (raw0 >= 1023 ? saH   : bf2f((unsigned short)(t0 >> 16)));
          float c1 = raw1 <= 0 ? c2pLO : (raw1 >= 1023 ? c2pHI : bf2f((unsigned short)t1));
          float p1 = raw1 <= 0 ? sbL   : (raw1 >= 1023 ? sbH   : bf2f((unsigned short)(t1 >> 16)));
          s0[rr] = (s0[rr] + c0 + p0) * CS;
          s1[rr] = (s1[rr] + c1 + p1) * CS;
        }
      }
    }

    // -------- online softmax (lane owns full row i)
    float vmax = s0[0];
    #pragma unroll
    for (int rr = 1; rr < 16; ++rr) vmax = fmaxf(vmax, s0[rr]);
    #pragma unroll
    for (int rr = 0; rr < 16; ++rr) vmax = fmaxf(vmax, s1[rr]);
    vmax = fmaxf(vmax, __shfl_xor(vmax, 32));
    float mx = fmaxf(m_, vmax);
    float fs = __builtin_amdgcn_exp2f(m_ - mx);
    m_ = mx;
    float sum = 0.f;
    #pragma unroll
    for (int rr = 0; rr < 16; ++rr) { s0[rr] = __builtin_amdgcn_exp2f(s0[rr] - mx); sum += s0[rr]; }
    #pragma unroll
    for (int rr = 0; rr < 16; ++rr) { s1[rr] = __builtin_amdgcn_exp2f(s1[rr] - mx); sum += s1[rr]; }
    sum += __shfl_xor(sum, 32);
    l_ = l_ * fs + sum;
    if (!__all(fs == 1.0f)) { ctx0 *= fs; ctx1 *= fs; }   // defer-rescale (exact)

    // -------- repack P -> B-frags: cvt-pack + cross-half shfl + select
    bf16x8 pf[4];
    #pragma unroll
    for (int kc = 0; kc < 4; ++kc) {
      const int c = kc & 1;
      const f32x16& sj = (kc >> 1) ? s1 : s0;
      unsigned X0 = pk2bf(sj[8*c+0], sj[8*c+1]);
      unsigned X1 = pk2bf(sj[8*c+2], sj[8*c+3]);
      unsigned Y0 = pk2bf(sj[8*c+4], sj[8*c+5]);
      unsigned Y1 = pk2bf(sj[8*c+6], sj[8*c+7]);
      unsigned sx0 = (unsigned)__shfl_xor((int)X0, 32);
      unsigned sx1 = (unsigned)__shfl_xor((int)X1, 32);
      unsigned sy0 = (unsigned)__shfl_xor((int)Y0, 32);
      unsigned sy1 = (unsigned)__shfl_xor((int)Y1, 32);
      u32x4 f;
      f[0] = h5 ? sy0 : X0;
      f[1] = h5 ? sy1 : X1;
      f[2] = h5 ? Y0 : sx0;
      f[3] = h5 ? Y1 : sx1;
      pf[kc] = __builtin_bit_cast(bf16x8, f);
    }

    // -------- PV: ctx = mfma(V^T, P) -> D[row=d][col=i]; lane owns ctx row i
    #pragma unroll
    for (int kc = 0; kc < 4; ++kc) {
      ctx0 = __builtin_amdgcn_mfma_f32_32x32x16_bf16(vf0[kc], pf[kc], ctx0, 0, 0, 0);
      ctx1 = __builtin_amdgcn_mfma_f32_32x32x16_bf16(vf1[kc], pf[kc], ctx1, 0, 0, 0);
    }
  }

  if constexpr (SPLIT == 1) {
    // -------- epilogue: lane owns row i = ig -> float4 stores
    float inv = 1.0f / l_;
    float* ob = out + (b * S_LEN + ig) * 768 + h * 64;
    #pragma unroll
    for (int q4 = 0; q4 < 4; ++q4) {
      float4 o0 = {ctx0[4*q4+0]*inv, ctx0[4*q4+1]*inv, ctx0[4*q4+2]*inv, ctx0[4*q4+3]*inv};
      *(float4*)(ob + 8 * q4 + 4 * h5) = o0;
      float4 o1 = {ctx1[4*q4+0]*inv, ctx1[4*q4+1]*inv, ctx1[4*q4+2]*inv, ctx1[4*q4+3]*inv};
      *(float4*)(ob + 32 + 8 * q4 + 4 * h5) = o1;
    }
  } else {
    // -------- partials: bf16 ctx + f32 (m,l)
    const int rowg = ((bh * 64 + it32) * SPLIT + sk) * 32 + iL;
    unsigned short* cp = ctxP + (size_t)rowg * 64;
    #pragma unroll
    for (int q4 = 0; q4 < 4; ++q4) {
      u16x4 p0, p1;
      #pragma unroll
      for (int e = 0; e < 4; ++e) { p0[e] = f2bf(ctx0[4*q4+e]); p1[e] = f2bf(ctx1[4*q4+e]); }
      *(u16x4*)(cp + 8 * q4 + 4 * h5) = p0;
      *(u16x4*)(cp + 32 + 8 * q4 + 4 * h5) = p1;
    }
    ((float2*)mlP)[rowg] = make_float2(m_, l_);
  }
}

// ---------------------------------------------------------------- combine
template<int SPLIT>
__global__ __launch_bounds__(256) void combine_kernel(
    const unsigned short* __restrict__ ctxP, const float* __restrict__ mlP,
    float* __restrict__ out) {
  int t = blockIdx.x * 256 + threadIdx.x;      // < 786432
  int row = t >> 4, dc = t & 15;
  int bh = row >> 11, i = row & 2047;
  int it32 = i >> 5, iL = i & 31;
  int pbase = ((bh * 64 + it32) * SPLIT) * 32 + iL;
  float m[SPLIT], lv[SPLIT];
  float M = -1e30f;
  #pragma unroll
  for (int s = 0; s < SPLIT; ++s) {
    float2 ml = ((const float2*)mlP)[pbase + s * 32];
    m[s] = ml.x; lv[s] = ml.y;
    M = fmaxf(M, ml.x);
  }
  float L = 0.f, w[SPLIT];
  #pragma unroll
  for (int s = 0; s < SPLIT; ++s) { w[s] = exp2f(m[s] - M); L += lv[s] * w[s]; }
  float4 o = {0.f, 0.f, 0.f, 0.f};
  #pragma unroll
  for (int s = 0; s < SPLIT; ++s) {
    u16x4 c = *(const u16x4*)(ctxP + (size_t)(pbase + s * 32) * 64 + dc * 4);
    o.x += bf2f(c[0]) * w[s]; o.y += bf2f(c[1]) * w[s];
    o.z += bf2f(c[2]) * w[s]; o.w += bf2f(c[3]) * w[s];
  }
  float invL = 1.0f / L;
  int b = bh / NH, h = bh - b * NH;
  float* op = out + (size_t)(b * S_LEN + i) * 768 + h * 64 + dc * 4;
  *(float4*)op = make_float4(o.x * invL, o.y * invL, o.z * invL, o.w * invL);
}

extern "C" void kernel_launch(void* const* d_in, const int* in_sizes, int n_in,
                              void* d_out, int out_size, void* d_ws, size_t ws_size,
                              hipStream_t stream) {
  (void)in_sizes; (void)n_in; (void)out_size;
  const float* Hx  = (const float*)d_in[0];
  const float* pos = (const float*)d_in[1];
  // d_in[2] = relative_pos: deterministic (i-j), recomputed inline -> unused
  const float* Wq  = (const float*)d_in[3];  const float* bq  = (const float*)d_in[4];
  const float* Wk  = (const float*)d_in[5];  const float* bk  = (const float*)d_in[6];
  const float* Wv  = (const float*)d_in[7];  const float* bv  = (const float*)d_in[8];
  const float* Wpq = (const float*)d_in[9];  const float* bpq = (const float*)d_in[10];
  const float* Wpk = (const float*)d_in[11]; const float* bpk = (const float*)d_in[12];
  unsigned short* ws = (unsigned short*)d_ws;

  // prep scratch lives in d_out's head (attn/combine rewrite all of d_out later)
  unsigned short* scratch = (unsigned short*)d_out;
  unsigned short* whi  = scratch;            // 327680 u16
  unsigned short* wlo  = scratch + 327680;   // 327680 u16
  unsigned short* wall = scratch + 655360;   // 245760 u16
  float*          ball = (float*)(scratch + 901120);  // 3840 f32

  float* c2p0g    = (float*)(ws + POSF);
  float* c2p1023g = c2p0g + 49152;
  float* p2c0g    = c2p0g + 98304;
  float* p2c1023g = c2p0g + 147456;

  // split-K partials after pos vecs
  const size_t base_u16 = POSF + 393216;     // 11,403,264 u16 = 22,806,528 B
  const size_t unit_bytes = 6684672;         // per split: ctx 6,291,456 + ml 393,216
  int SPLIT = (ws_size >= base_u16 * 2 + 4 * unit_bytes) ? 4
            : (ws_size >= base_u16 * 2 + 2 * unit_bytes) ? 2 : 1;
  unsigned short* ctxP = ws + base_u16;
  float* mlP = (float*)(ctxP + (size_t)SPLIT * 3145728);

  prep_kernel<<<2255, 256, 0, stream>>>(Hx, pos, Wq, Wk, Wv, Wpk, Wpq,
                                        bq, bk, bv, bpk, bpq, whi, wlo, wall, ball);
  proj_gemm<<<2688, 256, 0, stream>>>(whi, wlo, wall, ball, ws);
  pos_dots<<<384, 256, 0, stream>>>(ws, c2p0g, c2p1023g, p2c0g, p2c1023g);

  float* outf = (float*)d_out;
  if (SPLIT == 4) {
    attn_kernel<4><<<1536 * 4, 64, 0, stream>>>(ws, outf, ctxP, mlP);
    combine_kernel<4><<<3072, 256, 0, stream>>>(ctxP, mlP, outf);
  } else if (SPLIT == 2) {
    attn_kernel<2><<<1536 * 2, 64, 0, stream>>>(ws, outf, ctxP, mlP);
    combine_kernel<2><<<3072, 256, 0, stream>>>(ctxP, mlP, outf);
  } else {
    attn_kernel<1><<<1536, 64, 0, stream>>>(ws, outf, ctxP, mlP);
  }
}

// Round 8
// 344.523 us; speedup vs baseline: 1.8301x; 1.2504x over previous
//
#include <hip/hip_runtime.h>
#include <math.h>

// DeBERTa disentangled self-attention, fused (MI355X / gfx950).
// B=2, S=2048, D=64, H=12, K_SPAN=512.
// score[i,j] = (q_i.k_j + q_i.pk[c] + k_j.pq[c]) / sqrt(192), c = clip(i-j+512,0,1023)
//
// prep:      fp32 -> bf16 hi/lo split of H|pos, bf16 W, biases (stride loop, 288 wgs).
// proj_gemm: MFMA 16x16x32, X = hi+lo, packed 8B stores; 4 tiles/block (672 wgs).
// pos_dots:  rank-1 clamp vectors (96 wgs).
// attn<SPLIT>: split-K flash attention. KEY (round 7): 1-wave workgroups cap at
//            ~1080 resident waves (wg-grain limit) -> 8 INDEPENDENT waves per wg
//            (512 thr, no barriers, per-wave 8KB table, 64KB LDS). 768 wgs.
//            jt interleaved across sk chunks for uniform wave duration.
//            VGPR note: (.,2) -> 128 VGPR no spill; (.,4) spilled (round 6, 2.2x).
// combine<SPLIT>: merge partials (768 wgs).

#define S_LEN 2048
#define NH    12
#define TWOK  1024
#define QSZ   3145728   // 24 * 2048 * 64
#define PSZ   786432    // 12 * 1024 * 64
#define POSF  11010048  // 3*QSZ + 2*PSZ (u16 elements)

typedef __bf16 bf16x8 __attribute__((ext_vector_type(8)));
typedef unsigned short u16x8 __attribute__((ext_vector_type(8)));
typedef unsigned short u16x4 __attribute__((ext_vector_type(4)));
typedef float f32x4  __attribute__((ext_vector_type(4)));
typedef float f32x16 __attribute__((ext_vector_type(16)));
typedef unsigned int u32x4 __attribute__((ext_vector_type(4)));

__device__ __forceinline__ unsigned short f2bf(float f) {
  return __builtin_bit_cast(unsigned short, (__bf16)f);
}
__device__ __forceinline__ unsigned pk2bf(float a, float b) {
  return ((unsigned)__builtin_bit_cast(unsigned short, (__bf16)b) << 16)
       | (unsigned)__builtin_bit_cast(unsigned short, (__bf16)a);
}
__device__ __forceinline__ float bf2f(unsigned short h) {
  return __builtin_bit_cast(float, ((unsigned)h) << 16);
}
__device__ __forceinline__ bf16x8 ld_bf8(const unsigned short* p) {
  return __builtin_bit_cast(bf16x8, *(const u16x8*)p);
}

// ---------------------------------------------------------------- prep (288 wgs)
__global__ __launch_bounds__(256) void prep_kernel(
    const float* __restrict__ Hx, const float* __restrict__ pos,
    const float* __restrict__ Wq, const float* __restrict__ Wk,
    const float* __restrict__ Wv, const float* __restrict__ Wpk,
    const float* __restrict__ Wpq,
    const float* __restrict__ bq, const float* __restrict__ bk,
    const float* __restrict__ bv, const float* __restrict__ bpk,
    const float* __restrict__ bpq,
    unsigned short* __restrict__ whi, unsigned short* __restrict__ wlo,
    unsigned short* __restrict__ wall, float* __restrict__ ball) {
  int t0 = blockIdx.x * 256 + threadIdx.x;
  for (int pass = 0; pass < 8; ++pass) {
    int idx = t0 + pass * 73728;
    if (idx < 327680) {                     // H (4096x64) then pos (1024x64): hi/lo split
      float v = (idx < 262144) ? Hx[idx] : pos[idx - 262144];
      __bf16 hi = (__bf16)v;
      float lo = v - (float)hi;
      whi[idx] = __builtin_bit_cast(unsigned short, hi);
      wlo[idx] = f2bf(lo);
    } else if (idx < 573440) {              // W: q,k,v,pk,pq -> bf16, 3840x64
      int k = idx - 327680;
      int mat = k / 49152, off = k - mat * 49152;
      const float* W = mat==0?Wq: mat==1?Wk: mat==2?Wv: mat==3?Wpk:Wpq;
      wall[k] = f2bf(W[off]);
    } else if (idx < 577280) {              // biases, 3840
      int k = idx - 573440;
      int mat = k / 768, off = k - mat * 768;
      const float* B = mat==0?bq: mat==1?bk: mat==2?bv: mat==3?bpk:bpq;
      ball[k] = B[off];
    }
  }
}

// ---------------------------------------------------------------- projection GEMM
// 4 tiles per block (672 wgs). Per tile: block 256 = 4 waves; 64 tokens x 64 oh.
__global__ __launch_bounds__(256) void proj_gemm(
    const unsigned short* __restrict__ whi, const unsigned short* __restrict__ wlo,
    const unsigned short* __restrict__ wall, const float* __restrict__ ball,
    unsigned short* __restrict__ ws) {
  unsigned short* qg  = ws;
  unsigned short* kg  = ws + QSZ;
  unsigned short* vtg = ws + 2 * QSZ;
  unsigned short* pkg = ws + 3 * QSZ;
  unsigned short* pqg = ws + 3 * QSZ + PSZ;

  int tid = threadIdx.x, w = tid >> 6, l = tid & 63, lg = l >> 4, lr = l & 15;

  for (int tt = 0; tt < 4; ++tt) {
    int tile = blockIdx.x * 4 + tt;
    int rbase, obase, wrow, isA;
    if (tile < 2304) { rbase = (tile / 36) * 64;        obase = (tile % 36) * 64; wrow = obase;        isA = 1; }
    else { int b2 = tile - 2304; rbase = 4096 + (b2 / 24) * 64; obase = (b2 % 24) * 64; wrow = 2304 + obase; isA = 0; }

    int mat = obase / 768;
    int h = (obase % 768) >> 6;            // uniform per tile
    int ohrow = wrow + w * 16;             // this wave's 16 W rows

    bf16x8 wf[2];
    #pragma unroll
    for (int ks = 0; ks < 2; ++ks)
      wf[ks] = ld_bf8(wall + (ohrow + lr) * 64 + ks * 32 + 8 * lg);

    if (isA && mat == 2) {
      // ---- V, swapped orientation -> vT packed stores
      float bias = ball[ohrow + lr];
      int d = w * 16 + lr;                 // oh & 63
      #pragma unroll
      for (int tg = 0; tg < 4; ++tg) {
        f32x4 acc = {0.f, 0.f, 0.f, 0.f};
        #pragma unroll
        for (int ks = 0; ks < 2; ++ks) {
          bf16x8 xh = ld_bf8(whi + (rbase + tg * 16 + lr) * 64 + ks * 32 + 8 * lg);
          bf16x8 xl = ld_bf8(wlo + (rbase + tg * 16 + lr) * 64 + ks * 32 + 8 * lg);
          acc = __builtin_amdgcn_mfma_f32_16x16x32_bf16(xh, wf[ks], acc, 0, 0, 0);
          acc = __builtin_amdgcn_mfma_f32_16x16x32_bf16(xl, wf[ks], acc, 0, 0, 0);
        }
        int tok0 = rbase + tg * 16 + 4 * lg;
        int bb = tok0 >> 11, i0 = tok0 & 2047, bh = bb * NH + h;
        u16x4 pv;
        #pragma unroll
        for (int e = 0; e < 4; ++e) pv[e] = f2bf(acc[e] + bias);
        *(u16x4*)(vtg + (size_t)(bh * 64 + d) * S_LEN + i0) = pv;
      }
    } else {
      // ---- q/k/pk/pq, row-major packed stores
      float4 bias4 = *(const float4*)(ball + ohrow + 4 * lg);
      int d0 = w * 16 + 4 * lg;            // oh & 63 quad base
      #pragma unroll
      for (int tg = 0; tg < 4; ++tg) {
        f32x4 acc = {0.f, 0.f, 0.f, 0.f};
        #pragma unroll
        for (int ks = 0; ks < 2; ++ks) {
          bf16x8 xh = ld_bf8(whi + (rbase + tg * 16 + lr) * 64 + ks * 32 + 8 * lg);
          bf16x8 xl = ld_bf8(wlo + (rbase + tg * 16 + lr) * 64 + ks * 32 + 8 * lg);
          acc = __builtin_amdgcn_mfma_f32_16x16x32_bf16(wf[ks], xh, acc, 0, 0, 0);
          acc = __builtin_amdgcn_mfma_f32_16x16x32_bf16(wf[ks], xl, acc, 0, 0, 0);
        }
        int tok = rbase + tg * 16 + lr;
        u16x4 pv;
        pv[0] = f2bf(acc[0] + bias4.x); pv[1] = f2bf(acc[1] + bias4.y);
        pv[2] = f2bf(acc[2] + bias4.z); pv[3] = f2bf(acc[3] + bias4.w);
        if (isA) {
          int bb = tok >> 11, i = tok & 2047, bh = bb * NH + h;
          unsigned short* dst = (mat == 0 ? qg : kg) + (size_t)(bh * S_LEN + i) * 64 + d0;
          *(u16x4*)dst = pv;
        } else {
          int prow = tok - 4096;
          unsigned short* dst = (mat == 0 ? pkg : pqg) + (size_t)(h * TWOK + prow) * 64 + d0;
          *(u16x4*)dst = pv;
        }
      }
    }
  }
}

// ---------------------------------------------------------------- pos_dots (96 wgs)
__global__ __launch_bounds__(256) void pos_dots(
    const unsigned short* __restrict__ ws, float* __restrict__ c2p0,
    float* __restrict__ c2p1023, float* __restrict__ p2c0,
    float* __restrict__ p2c1023) {
  int t0 = blockIdx.x * 256 + threadIdx.x;
  for (int pass = 0; pass < 4; ++pass) {
    int t = t0 + pass * 24576;                // [0, 98304)
    int isK = t >= 49152;
    int row = isK ? t - 49152 : t;            // bh*2048 + i
    int h = (row >> 11) % NH;
    const unsigned short* src = ws + (isK ? QSZ : 0) + row * 64;
    const unsigned short* pA = ws + 3 * QSZ + (isK ? PSZ : 0) + (h * TWOK) * 64;
    const unsigned short* pB = pA + 1023 * 64;
    float a0 = 0.f, a1 = 0.f;
    #pragma unroll
    for (int c = 0; c < 8; ++c) {
      u16x8 xv = *(const u16x8*)(src + c * 8);
      u16x8 av = *(const u16x8*)(pA + c * 8);
      u16x8 bv = *(const u16x8*)(pB + c * 8);
      #pragma unroll
      for (int e = 0; e < 8; ++e) {
        float x = bf2f(xv[e]);
        a0 += x * bf2f(av[e]);
        a1 += x * bf2f(bv[e]);
      }
    }
    if (isK) { p2c0[row] = a0; p2c1023[row] = a1; }
    else     { c2p0[row] = a0; c2p1023[row] = a1; }
  }
}

// ---------------------------------------------------------------- fused attention
// 512 thr = 8 INDEPENDENT waves (no barriers); grid 768 wgs; per-wave 8KB table.
// Wave unit u = (bid>>3)*8 + wid; sk = u&3 (jt interleaved), v=u>>2: bh_l=v%3, it32=v/3.
template<int SPLIT>
__global__ __launch_bounds__(512, 2) void attn_kernel(
    const unsigned short* __restrict__ ws, float* __restrict__ out,
    unsigned short* __restrict__ ctxP, float* __restrict__ mlP) {
  const unsigned short* qg  = ws;
  const unsigned short* kg  = ws + QSZ;
  const unsigned short* vtg = ws + 2 * QSZ;
  const unsigned short* pkg = ws + 3 * QSZ;
  const unsigned short* pqg = ws + 3 * QSZ + PSZ;
  const float* c2p0g    = (const float*)(ws + POSF);
  const float* c2p1023g = c2p0g + 49152;
  const float* p2c0g    = c2p0g + 98304;
  const float* p2c1023g = c2p0g + 147456;

  __shared__ __align__(16) unsigned int tbl2all[8 * 2048];   // 8 waves x 8KB
  unsigned int* tbl2 = tbl2all + (threadIdx.x >> 6) * 2048;

  const int bid = blockIdx.x;
  const int g = bid & 7;                       // ~XCD (round-robin dispatch)
  const int wid = threadIdx.x >> 6;
  const int u = (bid >> 3) * 8 + wid;          // per-XCD unit [0, 96*8)
  const int sk = u & (SPLIT - 1);
  const int v = u / SPLIT;                     // [0, 192)
  const int bh = 8 * (v % 3) + g;              // XCD g owns bh {g, g+8, g+16}
  const int it32 = v / 3;                      // 0..63
  const int b = bh / NH, h = bh - b * NH;
  const int l = threadIdx.x & 63;
  const int iL = l & 31, h5 = l >> 5;
  const int i0w = it32 * 32;
  const int ig = i0w + iL;

  const unsigned short* qb  = qg  + bh * (S_LEN * 64);
  const unsigned short* kb  = kg  + bh * (S_LEN * 64);
  const unsigned short* vb  = vtg + bh * (64 * S_LEN);
  const unsigned short* pkb = pkg + h * (TWOK * 64);
  const unsigned short* pqb = pqg + h * (TWOK * 64);

  const float CS = 1.4426950408889634f / sqrtf(192.0f);  // log2(e)/sqrt(3*64)

  // Q as B-frag: lane holds Q[col=i=iL][k = kc*16 + 8*h5 + e]
  bf16x8 qf[4];
  #pragma unroll
  for (int kc = 0; kc < 4; ++kc)
    qf[kc] = ld_bf8(qb + ig * 64 + kc * 16 + 8 * h5);

  const float c2pLO = c2p0g[bh * S_LEN + ig];
  const float c2pHI = c2p1023g[bh * S_LEN + ig];

  f32x16 ctx0 = 0.f, ctx1 = 0.f;
  float m_ = -1e30f, l_ = 0.f;

  for (int t = 0; t < 32 / SPLIT; ++t) {
    const int jt = sk + t * SPLIT;             // interleaved: uniform banded mix
    const int j0 = jt * 64;
    const int D0w = 512 + i0w - j0;        // wave-uniform
    const int rlo = D0w - 63;              // raw rel min over tile
    const int rhi = rlo + 94;              // raw rel max

    // K as A-frag (rows j) - reused as B-frag (cols j) for p2c bands
    bf16x8 kf0[4], kf1[4];
    #pragma unroll
    for (int kc = 0; kc < 4; ++kc) {
      kf0[kc] = ld_bf8(kb + (j0 + iL) * 64 + kc * 16 + 8 * h5);
      kf1[kc] = ld_bf8(kb + (j0 + 32 + iL) * 64 + kc * 16 + 8 * h5);
    }
    // V^T frags hoisted
    bf16x8 vf0[4], vf1[4];
    #pragma unroll
    for (int kc = 0; kc < 4; ++kc) {
      vf0[kc] = ld_bf8(vb + (iL) * S_LEN + j0 + kc * 16 + 8 * h5);
      vf1[kc] = ld_bf8(vb + (32 + iL) * S_LEN + j0 + kc * 16 + 8 * h5);
    }

    // QK^T swapped: D[row=j][col=i]; lane: i=iL, j = 32*js + (r&3)+8*(r>>2)+4*h5
    f32x16 s0 = 0.f, s1 = 0.f;
    #pragma unroll
    for (int kc = 0; kc < 4; ++kc) {
      s0 = __builtin_amdgcn_mfma_f32_32x32x16_bf16(kf0[kc], qf[kc], s0, 0, 0, 0);
      s1 = __builtin_amdgcn_mfma_f32_32x32x16_bf16(kf1[kc], qf[kc], s1, 0, 0, 0);
    }

    if (rlo >= 1023) {
      // -------- fully clamped high
      float pa = p2c1023g[bh * S_LEN + j0 + iL];
      float pb = p2c1023g[bh * S_LEN + j0 + 32 + iL];
      #pragma unroll
      for (int rr = 0; rr < 16; ++rr) {
        const int j32 = (rr & 3) + 8 * (rr >> 2) + 4 * h5;
        s0[rr] = (s0[rr] + c2pHI + __shfl(pa, j32)) * CS;
        s1[rr] = (s1[rr] + c2pHI + __shfl(pb, j32)) * CS;
      }
    } else if (rhi <= 0) {
      // -------- fully clamped low
      float pa = p2c0g[bh * S_LEN + j0 + iL];
      float pb = p2c0g[bh * S_LEN + j0 + 32 + iL];
      #pragma unroll
      for (int rr = 0; rr < 16; ++rr) {
        const int j32 = (rr & 3) + 8 * (rr >> 2) + 4 * h5;
        s0[rr] = (s0[rr] + c2pLO + __shfl(pa, j32)) * CS;
        s1[rr] = (s1[rr] + c2pLO + __shfl(pb, j32)) * CS;
      }
    } else {
      // -------- banded path
      const int rminc = rlo < 0 ? 0 : rlo;
      const int rmaxc = rhi > 1023 ? 1023 : rhi;
      const int bstart = rminc > 928 ? 928 : rminc;
      const int nbands = ((rmaxc - bstart) >> 5) + 1;     // <= 3
      const int base = D0w - bstart;
      const int interior = (rlo >= 0) & (rhi <= 1023);

      for (int nb = 0; nb < nbands; ++nb) {
        const int relb0 = nb * 32;
        const bool needC  = (relb0 <= base + 31) && (relb0 + 31 >= base - 63);
        const bool needP0 = (relb0 <= base + 31) && (relb0 + 31 >= base - 31);
        const bool needP1 = (relb0 <= base - 1)  && (relb0 + 31 >= base - 63);
        const int rrow = bstart + relb0 + iL;

        if (needC) {
          f32x16 ac = 0.f;
          #pragma unroll
          for (int kc = 0; kc < 4; ++kc) {
            bf16x8 fk = ld_bf8(pkb + rrow * 64 + kc * 16 + 8 * h5);
            ac = __builtin_amdgcn_mfma_f32_32x32x16_bf16(fk, qf[kc], ac, 0, 0, 0);
          }
          // scatter: value (i=iL, rel) -> slot [js = base+iL-relb][iL], low u16
          #pragma unroll
          for (int q4 = 0; q4 < 4; ++q4) {
            #pragma unroll
            for (int e = 0; e < 4; ++e) {
              const int relb = relb0 + 8 * q4 + 4 * h5 + e;
              const int js = base + iL - relb;
              if (js >= 0 && js < 64)
                ((unsigned short*)tbl2)[(js * 32 + iL) * 2] = f2bf(ac[4 * q4 + e]);
            }
          }
        }
        if (needP0 | needP1) {
          f32x16 a0 = 0.f, a1 = 0.f;
          #pragma unroll
          for (int kc = 0; kc < 4; ++kc) {
            bf16x8 fq = ld_bf8(pqb + rrow * 64 + kc * 16 + 8 * h5);
            if (needP0) a0 = __builtin_amdgcn_mfma_f32_32x32x16_bf16(fq, kf0[kc], a0, 0, 0, 0);
            if (needP1) a1 = __builtin_amdgcn_mfma_f32_32x32x16_bf16(fq, kf1[kc], a1, 0, 0, 0);
          }
          // scatter: value (j=jc, rel) -> slot [jc][i2 = relb+jc-base], high u16
          #pragma unroll
          for (int q4 = 0; q4 < 4; ++q4) {
            #pragma unroll
            for (int e = 0; e < 4; ++e) {
              const int relb = relb0 + 8 * q4 + 4 * h5 + e;
              if (needP0) {
                const int i2 = relb + iL - base;
                if (i2 >= 0 && i2 < 32)
                  ((unsigned short*)tbl2)[(iL * 32 + i2) * 2 + 1] = f2bf(a0[4 * q4 + e]);
              }
              if (needP1) {
                const int i2 = relb + 32 + iL - base;
                if (i2 >= 0 && i2 < 32)
                  ((unsigned short*)tbl2)[((32 + iL) * 32 + i2) * 2 + 1] = f2bf(a1[4 * q4 + e]);
              }
            }
          }
        }
      }
      asm volatile("s_waitcnt lgkmcnt(0)" ::: "memory");  // wave-local write->read

      if (interior) {
        #pragma unroll
        for (int rr = 0; rr < 16; ++rr) {
          const int j32 = (rr & 3) + 8 * (rr >> 2) + 4 * h5;
          const unsigned t0 = tbl2[j32 * 32 + iL];
          const unsigned t1 = tbl2[(32 + j32) * 32 + iL];
          s0[rr] = (s0[rr] + bf2f((unsigned short)t0) + bf2f((unsigned short)(t0 >> 16))) * CS;
          s1[rr] = (s1[rr] + bf2f((unsigned short)t1) + bf2f((unsigned short)(t1 >> 16))) * CS;
        }
      } else {
        const int D0 = D0w + iL;
        float paL = p2c0g[bh * S_LEN + j0 + iL];
        float paH = p2c1023g[bh * S_LEN + j0 + iL];
        float pbL = p2c0g[bh * S_LEN + j0 + 32 + iL];
        float pbH = p2c1023g[bh * S_LEN + j0 + 32 + iL];
        #pragma unroll
        for (int rr = 0; rr < 16; ++rr) {
          const int j32 = (rr & 3) + 8 * (rr >> 2) + 4 * h5;
          const int raw0 = D0 - j32, raw1 = D0 - 32 - j32;
          const unsigned t0 = tbl2[j32 * 32 + iL];
          const unsigned t1 = tbl2[(32 + j32) * 32 + iL];
          const float saL = __shfl(paL, j32), saH = __shfl(paH, j32);
          const float sbL = __shfl(pbL, j32), sbH = __shfl(pbH, j32);
          float c0 = raw0 <= 0 ? c2pLO : (raw0 >= 1023 ? c2pHI : bf2f((unsigned short)t0));
          float p0 = raw0 <= 0 ? saL   : (raw0 >= 1023 ? saH   : bf2f((unsigned short)(t0 >> 16)));
          float c1 = raw1 <= 0 ? c2pLO : (raw1 >= 1023 ? c2pHI : bf2f((unsigned short)t1));
          float p1 = raw1 <= 0 ? sbL   : (raw1 >= 1023 ? sbH   : bf2f((unsigned short)(t1 >> 16)));
          s0[rr] = (s0[rr] + c0 + p0) * CS;
          s1[rr] = (s1[rr] + c1 + p1) * CS;
        }
      }
    }

    // -------- online softmax (lane owns full row i)
    float vmax = s0[0];
    #pragma unroll
    for (int rr = 1; rr < 16; ++rr) vmax = fmaxf(vmax, s0[rr]);
    #pragma unroll
    for (int rr = 0; rr < 16; ++rr) vmax = fmaxf(vmax, s1[rr]);
    vmax = fmaxf(vmax, __shfl_xor(vmax, 32));
    float mx = fmaxf(m_, vmax);
    float fs = __builtin_amdgcn_exp2f(m_ - mx);
    m_ = mx;
    float sum = 0.f;
    #pragma unroll
    for (int rr = 0; rr < 16; ++rr) { s0[rr] = __builtin_amdgcn_exp2f(s0[rr] - mx); sum += s0[rr]; }
    #pragma unroll
    for (int rr = 0; rr < 16; ++rr) { s1[rr] = __builtin_amdgcn_exp2f(s1[rr] - mx); sum += s1[rr]; }
    sum += __shfl_xor(sum, 32);
    l_ = l_ * fs + sum;
    if (!__all(fs == 1.0f)) { ctx0 *= fs; ctx1 *= fs; }   // defer-rescale (exact)

    // -------- repack P -> B-frags: cvt-pack + cross-half shfl + select
    bf16x8 pf[4];
    #pragma unroll
    for (int kc = 0; kc < 4; ++kc) {
      const int c = kc & 1;
      const f32x16& sj = (kc >> 1) ? s1 : s0;
      unsigned X0 = pk2bf(sj[8*c+0], sj[8*c+1]);
      unsigned X1 = pk2bf(sj[8*c+2], sj[8*c+3]);
      unsigned Y0 = pk2bf(sj[8*c+4], sj[8*c+5]);
      unsigned Y1 = pk2bf(sj[8*c+6], sj[8*c+7]);
      unsigned sx0 = (unsigned)__shfl_xor((int)X0, 32);
      unsigned sx1 = (unsigned)__shfl_xor((int)X1, 32);
      unsigned sy0 = (unsigned)__shfl_xor((int)Y0, 32);
      unsigned sy1 = (unsigned)__shfl_xor((int)Y1, 32);
      u32x4 f;
      f[0] = h5 ? sy0 : X0;
      f[1] = h5 ? sy1 : X1;
      f[2] = h5 ? Y0 : sx0;
      f[3] = h5 ? Y1 : sx1;
      pf[kc] = __builtin_bit_cast(bf16x8, f);
    }

    // -------- PV: ctx = mfma(V^T, P) -> D[row=d][col=i]; lane owns ctx row i
    #pragma unroll
    for (int kc = 0; kc < 4; ++kc) {
      ctx0 = __builtin_amdgcn_mfma_f32_32x32x16_bf16(vf0[kc], pf[kc], ctx0, 0, 0, 0);
      ctx1 = __builtin_amdgcn_mfma_f32_32x32x16_bf16(vf1[kc], pf[kc], ctx1, 0, 0, 0);
    }
  }

  if constexpr (SPLIT == 1) {
    // -------- epilogue: lane owns row i = ig -> float4 stores
    float inv = 1.0f / l_;
    float* ob = out + (b * S_LEN + ig) * 768 + h * 64;
    #pragma unroll
    for (int q4 = 0; q4 < 4; ++q4) {
      float4 o0 = {ctx0[4*q4+0]*inv, ctx0[4*q4+1]*inv, ctx0[4*q4+2]*inv, ctx0[4*q4+3]*inv};
      *(float4*)(ob + 8 * q4 + 4 * h5) = o0;
      float4 o1 = {ctx1[4*q4+0]*inv, ctx1[4*q4+1]*inv, ctx1[4*q4+2]*inv, ctx1[4*q4+3]*inv};
      *(float4*)(ob + 32 + 8 * q4 + 4 * h5) = o1;
    }
  } else {
    // -------- partials: bf16 ctx + f32 (m,l)
    const int rowg = ((bh * 64 + it32) * SPLIT + sk) * 32 + iL;
    unsigned short* cp = ctxP + (size_t)rowg * 64;
    #pragma unroll
    for (int q4 = 0; q4 < 4; ++q4) {
      u16x4 p0, p1;
      #pragma unroll
      for (int e = 0; e < 4; ++e) { p0[e] = f2bf(ctx0[4*q4+e]); p1[e] = f2bf(ctx1[4*q4+e]); }
      *(u16x4*)(cp + 8 * q4 + 4 * h5) = p0;
      *(u16x4*)(cp + 32 + 8 * q4 + 4 * h5) = p1;
    }
    ((float2*)mlP)[rowg] = make_float2(m_, l_);
  }
}

// ---------------------------------------------------------------- combine (768 wgs)
template<int SPLIT>
__global__ __launch_bounds__(256) void combine_kernel(
    const unsigned short* __restrict__ ctxP, const float* __restrict__ mlP,
    float* __restrict__ out) {
  int t0 = blockIdx.x * 256 + threadIdx.x;
  for (int pass = 0; pass < 4; ++pass) {
    int t = t0 + pass * 196608;                // < 786432
    int row = t >> 4, dc = t & 15;
    int bh = row >> 11, i = row & 2047;
    int it32 = i >> 5, iL = i & 31;
    int pbase = ((bh * 64 + it32) * SPLIT) * 32 + iL;
    float m[SPLIT], lv[SPLIT];
    float M = -1e30f;
    #pragma unroll
    for (int s = 0; s < SPLIT; ++s) {
      float2 ml = ((const float2*)mlP)[pbase + s * 32];
      m[s] = ml.x; lv[s] = ml.y;
      M = fmaxf(M, ml.x);
    }
    float L = 0.f, w[SPLIT];
    #pragma unroll
    for (int s = 0; s < SPLIT; ++s) { w[s] = exp2f(m[s] - M); L += lv[s] * w[s]; }
    float4 o = {0.f, 0.f, 0.f, 0.f};
    #pragma unroll
    for (int s = 0; s < SPLIT; ++s) {
      u16x4 c = *(const u16x4*)(ctxP + (size_t)(pbase + s * 32) * 64 + dc * 4);
      o.x += bf2f(c[0]) * w[s]; o.y += bf2f(c[1]) * w[s];
      o.z += bf2f(c[2]) * w[s]; o.w += bf2f(c[3]) * w[s];
    }
    float invL = 1.0f / L;
    int b = bh / NH, h = bh - b * NH;
    float* op = out + (size_t)(b * S_LEN + i) * 768 + h * 64 + dc * 4;
    *(float4*)op = make_float4(o.x * invL, o.y * invL, o.z * invL, o.w * invL);
  }
}

extern "C" void kernel_launch(void* const* d_in, const int* in_sizes, int n_in,
                              void* d_out, int out_size, void* d_ws, size_t ws_size,
                              hipStream_t stream) {
  (void)in_sizes; (void)n_in; (void)out_size;
  const float* Hx  = (const float*)d_in[0];
  const float* pos = (const float*)d_in[1];
  // d_in[2] = relative_pos: deterministic (i-j), recomputed inline -> unused
  const float* Wq  = (const float*)d_in[3];  const float* bq  = (const float*)d_in[4];
  const float* Wk  = (const float*)d_in[5];  const float* bk  = (const float*)d_in[6];
  const float* Wv  = (const float*)d_in[7];  const float* bv  = (const float*)d_in[8];
  const float* Wpq = (const float*)d_in[9];  const float* bpq = (const float*)d_in[10];
  const float* Wpk = (const float*)d_in[11]; const float* bpk = (const float*)d_in[12];
  unsigned short* ws = (unsigned short*)d_ws;

  // prep scratch lives in d_out's head (attn/combine rewrite all of d_out later)
  unsigned short* scratch = (unsigned short*)d_out;
  unsigned short* whi  = scratch;            // 327680 u16
  unsigned short* wlo  = scratch + 327680;   // 327680 u16
  unsigned short* wall = scratch + 655360;   // 245760 u16
  float*          ball = (float*)(scratch + 901120);  // 3840 f32

  float* c2p0g    = (float*)(ws + POSF);
  float* c2p1023g = c2p0g + 49152;
  float* p2c0g    = c2p0g + 98304;
  float* p2c1023g = c2p0g + 147456;

  // split-K partials after pos vecs
  const size_t base_u16 = POSF + 393216;     // 11,403,264 u16 = 22,806,528 B
  const size_t unit_bytes = 6684672;         // per split: ctx 6,291,456 + ml 393,216
  int SPLIT = (ws_size >= base_u16 * 2 + 4 * unit_bytes) ? 4
            : (ws_size >= base_u16 * 2 + 2 * unit_bytes) ? 2 : 1;
  unsigned short* ctxP = ws + base_u16;
  float* mlP = (float*)(ctxP + (size_t)SPLIT * 3145728);

  prep_kernel<<<288, 256, 0, stream>>>(Hx, pos, Wq, Wk, Wv, Wpk, Wpq,
                                       bq, bk, bv, bpk, bpq, whi, wlo, wall, ball);
  proj_gemm<<<672, 256, 0, stream>>>(whi, wlo, wall, ball, ws);
  pos_dots<<<96, 256, 0, stream>>>(ws, c2p0g, c2p1023g, p2c0g, p2c1023g);

  float* outf = (float*)d_out;
  if (SPLIT == 4) {
    attn_kernel<4><<<768, 512, 0, stream>>>(ws, outf, ctxP, mlP);
    combine_kernel<4><<<768, 256, 0, stream>>>(ctxP, mlP, outf);
  } else if (SPLIT == 2) {
    attn_kernel<2><<<384, 512, 0, stream>>>(ws, outf, ctxP, mlP);
    combine_kernel<2><<<768, 256, 0, stream>>>(ctxP, mlP, outf);
  } else {
    attn_kernel<1><<<192, 512, 0, stream>>>(ws, outf, ctxP, mlP);
  }
}